// Round 6
// baseline (349.505 us; speedup 1.0000x reference)
//
#include <hip/hip_runtime.h>
#include <hip/hip_bf16.h>
#include <cstdint>
#include <cstddef>

typedef __attribute__((ext_vector_type(8))) short bf16x8;
typedef __attribute__((ext_vector_type(4))) short bf16x4;
typedef __attribute__((ext_vector_type(4))) float f32x4;
typedef __attribute__((ext_vector_type(2))) unsigned int u32x2;

#define NH 16
#define DK 64
#define SEQ 2048
#define DM 1024
#define QSCALE 0.18033688011112042f  // 0.125 * log2(e): softmax uses exp2

// RTNE (cvt kernels, VALU free there)
__device__ __forceinline__ short f2bf(float f) {
    union { float f; unsigned u; } x; x.f = f;
    unsigned r = x.u + 0x7fffu + ((x.u >> 16) & 1u);
    return (short)(r >> 16);
}

// fast pack: two f32 -> bf16 pair (round-half-up), one v_perm_b32
__device__ __forceinline__ unsigned pk2(float a, float b) {
    union { float f; unsigned u; } x, y; x.f = a; y.f = b;
    return __builtin_amdgcn_perm(y.u + 0x8000u, x.u + 0x8000u, 0x07060302u);
}

__device__ __forceinline__ void glds16(const short* g, short* l) {
    __builtin_amdgcn_global_load_lds((const __attribute__((address_space(1))) unsigned int*)g,
                                     (__attribute__((address_space(3))) unsigned int*)l, 16, 0, 0);
}

// ---------------------------------------------------------------------------
// fused fp32->bf16 conversion: 3 x-inputs (4096 blocks each) + 4 weights (512 each)
// ---------------------------------------------------------------------------
__global__ __launch_bounds__(256)
void cvt_all(const float* __restrict__ xq, const float* __restrict__ xk, const float* __restrict__ xv,
             const float* __restrict__ Wq, const float* __restrict__ Wk,
             const float* __restrict__ Wv, const float* __restrict__ Wo,
             short* __restrict__ xb0, short* __restrict__ xb1, short* __restrict__ xb2,
             short* __restrict__ Wb)
{
    const int bid = blockIdx.x;
    const float* src;
    short* dst;
    float sc = 1.0f;
    int i;
    if (bid < 12288) {
        int z = bid >> 12;
        src = (z == 0) ? xq : (z == 1) ? xk : xv;
        dst = (z == 0) ? xb0 : (z == 1) ? xb1 : xb2;
        i = (bid & 4095) * 2048 + threadIdx.x * 8;
    } else {
        int wb = bid - 12288;
        int z = wb >> 9;
        src = (z == 0) ? Wq : (z == 1) ? Wk : (z == 2) ? Wv : Wo;
        dst = Wb + (size_t)z * DM * DM;
        sc = (z == 0) ? QSCALE : 1.0f;  // fold q scale into Wq
        i = (wb & 511) * 2048 + threadIdx.x * 8;
    }
    float4 a = *(const float4*)&src[i];
    float4 b = *(const float4*)&src[i + 4];
    bf16x8 o = { f2bf(a.x * sc), f2bf(a.y * sc), f2bf(a.z * sc), f2bf(a.w * sc),
                 f2bf(b.x * sc), f2bf(b.y * sc), f2bf(b.z * sc), f2bf(b.w * sc) };
    *(bf16x8*)&dst[i] = o;
}

// fallback converters (sequential path)
__global__ __launch_bounds__(256)
void cvt_x(const float* __restrict__ src, short* __restrict__ dst)
{
    int i = (blockIdx.x * 256 + threadIdx.x) * 8;
    float4 a = *(const float4*)&src[i];
    float4 b = *(const float4*)&src[i + 4];
    bf16x8 o = { f2bf(a.x), f2bf(a.y), f2bf(a.z), f2bf(a.w),
                 f2bf(b.x), f2bf(b.y), f2bf(b.z), f2bf(b.w) };
    *(bf16x8*)&dst[i] = o;
}

__global__ __launch_bounds__(256)
void cvt_w(const float* __restrict__ Wq, const float* __restrict__ Wk,
           const float* __restrict__ Wv, const float* __restrict__ Wo,
           short* __restrict__ dst)
{
    int z = blockIdx.y;
    const float* s = (z == 0) ? Wq : (z == 1) ? Wk : (z == 2) ? Wv : Wo;
    float sc = (z == 0) ? QSCALE : 1.0f;
    int i = (blockIdx.x * 256 + threadIdx.x) * 8;
    float4 a = *(const float4*)&s[i];
    float4 b = *(const float4*)&s[i + 4];
    bf16x8 o = { f2bf(a.x * sc), f2bf(a.y * sc), f2bf(a.z * sc), f2bf(a.w * sc),
                 f2bf(b.x * sc), f2bf(b.y * sc), f2bf(b.z * sc), f2bf(b.w * sc) };
    *(bf16x8*)&dst[(size_t)z * DM * DM + i] = o;
}

// ---------------------------------------------------------------------------
// bf16 GEMM core: 128x128 tile, BK=32, global_load_lds width=16, XOR swizzle
// (applied on global source side), single-barrier double-buffered pipeline
// with statically distinct LDS buffers (unroll x2).
// ---------------------------------------------------------------------------
#define GEMM_STAGE(Adst, Bdst, kk)                                                         \
    glds16(&P0_[(size_t)(OFF0_ + r0) * DM + (kk) + c0], &Adst[g0 * 8]);                    \
    glds16(&P0_[(size_t)(OFF0_ + r1) * DM + (kk) + c1], &Adst[g1 * 8]);                    \
    glds16(&P1_[(size_t)(OFF1_ + r0) * DM + (kk) + c0], &Bdst[g0 * 8]);                    \
    glds16(&P1_[(size_t)(OFF1_ + r1) * DM + (kk) + c1], &Bdst[g1 * 8]);

#define GEMM_TILE(Asrc, Bsrc)                                                              \
    {                                                                                      \
        bf16x8 a[4], b[4];                                                                 \
        _Pragma("unroll")                                                                  \
        for (int i = 0; i < 4; i++) {                                                      \
            int row = wm + i * 16 + l15;                                                   \
            a[i] = *(bf16x8*)&Asrc[row * 32 + (quad ^ ((row >> 1) & 3)) * 8];              \
        }                                                                                  \
        _Pragma("unroll")                                                                  \
        for (int j = 0; j < 4; j++) {                                                      \
            int row = wn + j * 16 + l15;                                                   \
            b[j] = *(bf16x8*)&Bsrc[row * 32 + (quad ^ ((row >> 1) & 3)) * 8];              \
        }                                                                                  \
        _Pragma("unroll")                                                                  \
        for (int i = 0; i < 4; i++)                                                        \
            _Pragma("unroll")                                                              \
            for (int j = 0; j < 4; j++)                                                    \
                acc[i][j] = __builtin_amdgcn_mfma_f32_16x16x32_bf16(a[i], b[j], acc[i][j], 0, 0, 0); \
    }

#define GEMM_CORE(P0, OFF0, P1, OFF1)                                                      \
    __shared__ short As0[128 * 32], As1[128 * 32];                                         \
    __shared__ short Bs0[128 * 32], Bs1[128 * 32];                                         \
    f32x4 acc[4][4] = {};                                                                  \
    const short* P0_ = (P0);  const int OFF0_ = (OFF0);                                    \
    const short* P1_ = (P1);  const int OFF1_ = (OFF1);                                    \
    const int t = threadIdx.x;                                                             \
    const int lane = t & 63;                                                               \
    const int w = t >> 6;                                                                  \
    const int wm = (w >> 1) * 64, wn = (w & 1) * 64;                                       \
    const int l15 = lane & 15, quad = lane >> 4;                                           \
    const int g0 = t, g1 = 256 + t;                                                        \
    const int r0 = g0 >> 2, r1 = g1 >> 2;                                                  \
    const int c0 = ((g0 & 3) ^ ((r0 >> 1) & 3)) * 8;                                       \
    const int c1 = ((g1 & 3) ^ ((r1 >> 1) & 3)) * 8;                                       \
    GEMM_STAGE(As0, Bs0, 0)                                                                \
    for (int k0 = 0; k0 < DM; k0 += 64) {                                                  \
        __syncthreads();                                                                   \
        GEMM_STAGE(As1, Bs1, k0 + 32)                                                      \
        GEMM_TILE(As0, Bs0)                                                                \
        __syncthreads();                                                                   \
        if (k0 + 64 < DM) { GEMM_STAGE(As0, Bs0, k0 + 64) }                                \
        GEMM_TILE(As1, Bs1)                                                                \
    }

// ---------------------------------------------------------------------------
// fused QKV projection GEMM. grid = (8, 64, nz); z = blockIdx.z + zoff.
// z=0: Q (swapped orient, b64 stores to [bh][s][64], bias*QSCALE)
// z=1: K (same, bias*1)
// z=2: V (normal orient, transposed store [bh][d][s])
// ---------------------------------------------------------------------------
__global__ __launch_bounds__(256)
void gemm_qkv(const short* __restrict__ x0, const short* __restrict__ x1, const short* __restrict__ x2,
              const short* __restrict__ Wball,
              const float* __restrict__ bq, const float* __restrict__ bk, const float* __restrict__ bv,
              short* __restrict__ qws, short* __restrict__ kws, short* __restrict__ vws,
              int zoff)
{
    const int z = blockIdx.z + zoff;
    const short* X = (z == 0) ? x0 : (z == 1) ? x1 : x2;
    const short* W = Wball + (size_t)z * DM * DM;
    const float* bias = (z == 0) ? bq : (z == 1) ? bk : bv;
    const float bscale = (z == 0) ? QSCALE : 1.0f;

    const int tn = blockIdx.x * 128;
    const int tm = blockIdx.y * 128;
    const int vm = (z == 2);

    GEMM_CORE(vm ? X : W, vm ? tm : tn, vm ? W : X, vm ? tn : tm)

    if (vm) {
        // V: [bh][d][s]; r-regs = 4 consecutive s -> b64 stores
#pragma unroll
        for (int j = 0; j < 4; j++) {
            int n = tn + wn + j * 16 + l15;
            float bn = bias[n];
            int h = n >> 6, d = n & 63;
#pragma unroll
            for (int i = 0; i < 4; i++) {
                int m0 = tm + wm + i * 16 + quad * 4;
                int bb = m0 >> 11, s0 = m0 & (SEQ - 1);
                u32x2 u = { pk2(acc[i][j][0] + bn, acc[i][j][1] + bn),
                            pk2(acc[i][j][2] + bn, acc[i][j][3] + bn) };
                *(u32x2*)&vws[((size_t)((bb * NH + h) * 64 + d)) * SEQ + s0] = u;
            }
        }
    } else {
        short* dst = (z == 0) ? qws : kws;
        // swapped: acc rows = features, cols = tokens -> b64 stores along d
#pragma unroll
        for (int i = 0; i < 4; i++) {
            int n0 = tn + wm + i * 16 + quad * 4;
            float4 b4 = *(const float4*)&bias[n0];
            int h = n0 >> 6, d0 = n0 & 63;
#pragma unroll
            for (int j = 0; j < 4; j++) {
                int m = tm + wn + j * 16 + l15;
                int bb = m >> 11, s = m & (SEQ - 1);
                u32x2 u = { pk2(acc[i][j][0] + b4.x * bscale, acc[i][j][1] + b4.y * bscale),
                            pk2(acc[i][j][2] + b4.z * bscale, acc[i][j][3] + b4.w * bscale) };
                *(u32x2*)&dst[((((size_t)(bb * NH + h)) * SEQ + s) << 6) + d0] = u;
            }
        }
    }
}

__global__ __launch_bounds__(256)
void out_proj(const short* __restrict__ A, const short* __restrict__ W,
              const float* __restrict__ bias, float* __restrict__ out)
{
    const int tn = blockIdx.x * 128;
    const int tm = blockIdx.y * 128;
    GEMM_CORE(A, tm, W, tn)

#pragma unroll
    for (int j = 0; j < 4; j++) {
        int n = tn + wn + j * 16 + l15;
        float bn = bias[n];
#pragma unroll
        for (int i = 0; i < 4; i++)
#pragma unroll
            for (int r = 0; r < 4; r++) {
                int m = tm + wm + i * 16 + quad * 4 + r;
                out[(size_t)m * DM + n] = acc[i][j][r] + bn;
            }
    }
}

// ---------------------------------------------------------------------------
// flash attention, transposed (S^T = K Q^T, O^T = V^T P^T), no-max softmax,
// denominator via ones-row MFMA. Single-barrier glds double-buffer pipeline.
// Q,K: bf16 [bh][s][64] (Q pre-scaled); V: bf16 [bh][d][s]; O: [b][s][h*64+d]
// grid = (B*H, S/128). LDS 52 KB -> 3 blocks/CU.
// ---------------------------------------------------------------------------
#define ATTN_STAGE(kt, Kdst, Vdst)                                                         \
    glds16(&K[base + (size_t)((kt) * 64 + rA) * DK + kcA], &Kdst[gA * 8]);                 \
    glds16(&K[base + (size_t)((kt) * 64 + rB) * DK + kcB], &Kdst[gB * 8]);                 \
    glds16(&V[vbase + (size_t)rA * SEQ + (kt) * 64 + kcA], &Vdst[gA * 8]);                 \
    glds16(&V[vbase + (size_t)rB * SEQ + (kt) * 64 + kcB], &Vdst[gB * 8]);

#define ATTN_TILE(KB, VB)                                                                  \
    {                                                                                      \
        f32x4 st[4][2] = {};                                                               \
        _Pragma("unroll")                                                                  \
        for (int kd = 0; kd < 2; kd++) {                                                   \
            _Pragma("unroll")                                                              \
            for (int mf = 0; mf < 4; mf++) {                                               \
                bf16x8 ka = *(bf16x8*)&KB[(mf * 16 + l15) * 64 + ((kd * 4 + quad) ^ l7) * 8]; \
                _Pragma("unroll")                                                          \
                for (int nq = 0; nq < 2; nq++)                                             \
                    st[mf][nq] = __builtin_amdgcn_mfma_f32_16x16x32_bf16(ka, qb[nq][kd], st[mf][nq], 0, 0, 0); \
            }                                                                              \
        }                                                                                  \
        _Pragma("unroll")                                                                  \
        for (int nq = 0; nq < 2; nq++) {                                                   \
            const int prow = (nq * 16 + l15) * 64;                                         \
            _Pragma("unroll")                                                              \
            for (int mf = 0; mf < 4; mf++) {                                               \
                _Pragma("unroll")                                                          \
                for (int r = 0; r < 4; r++)                                                \
                    st[mf][nq][r] = __builtin_amdgcn_exp2f(st[mf][nq][r]);                 \
                u32x2 u = { pk2(st[mf][nq][0], st[mf][nq][1]),                             \
                            pk2(st[mf][nq][2], st[mf][nq][3]) };                           \
                *(u32x2*)&Pt[w][prow + (((mf * 2 + (quad >> 1)) ^ l7) * 8) + (quad & 1) * 4] = u; \
            }                                                                              \
        }                                                                                  \
        _Pragma("unroll")                                                                  \
        for (int kk = 0; kk < 2; kk++) {                                                   \
            bf16x8 pb[2];                                                                  \
            _Pragma("unroll")                                                              \
            for (int nq = 0; nq < 2; nq++)                                                 \
                pb[nq] = *(bf16x8*)&Pt[w][(nq * 16 + l15) * 64 + ((kk * 4 + quad) ^ l7) * 8]; \
            _Pragma("unroll")                                                              \
            for (int mfd = 0; mfd < 5; mfd++) {                                            \
                bf16x8 va = *(bf16x8*)&VB[(mfd * 16 + l15) * 64 + ((kk * 4 + quad) ^ l7) * 8]; \
                _Pragma("unroll")                                                          \
                for (int nq = 0; nq < 2; nq++)                                             \
                    oT[mfd][nq] = __builtin_amdgcn_mfma_f32_16x16x32_bf16(va, pb[nq], oT[mfd][nq], 0, 0, 0); \
            }                                                                              \
        }                                                                                  \
    }

__global__ __launch_bounds__(256, 3)
void attn(const short* __restrict__ Q, const short* __restrict__ K, const short* __restrict__ V,
          short* __restrict__ O)
{
    const int bh = blockIdx.x;
    const int b = bh >> 4, h = bh & 15;
    const int qt = blockIdx.y;
    const size_t base = (size_t)bh * SEQ * DK;
    const size_t vbase = (size_t)bh * DK * SEQ;

    const int t = threadIdx.x;
    const int lane = t & 63;
    const int w = t >> 6;
    const int l15 = lane & 15, quad = lane >> 4;
    const int l7 = l15 & 7;

    __shared__ short Kt0[64 * 64], Kt1[64 * 64];       // [key][d], swizzled
    __shared__ short Vt0[80 * 64], Vt1[80 * 64];       // [d][key]; rows 64..79: ones-trick
    __shared__ short Pt[4][32 * 64];                   // per-wave P^T [qrow][key]

    // ones rows (row 64 = 1.0 bf16, 65..79 = 0) in both buffers; uniform rows -> swizzle-safe
    {
        int rrow = (t >> 3) & 15;
        short val = (rrow == 0) ? (short)0x3F80 : (short)0;
        bf16x8 fill = { val, val, val, val, val, val, val, val };
        short* Vx = (t < 128) ? Vt0 : Vt1;
        *(bf16x8*)&Vx[(64 + rrow) * 64 + (t & 7) * 8] = fill;
    }

    // staging: granule g -> LDS linear g*8; global col XOR-swizzled by row
    const int gA = t, gB = t + 256;
    const int rA = gA >> 3, rB = gB >> 3;              // rows 0..31 / 32..63
    const int kcA = ((gA & 7) ^ (rA & 7)) * 8;
    const int kcB = ((gB & 7) ^ (rB & 7)) * 8;

    bf16x8 qb[2][2];
    const int qrow0 = qt * 128 + w * 32;
#pragma unroll
    for (int nq = 0; nq < 2; nq++)
#pragma unroll
        for (int kd = 0; kd < 2; kd++)
            qb[nq][kd] = *(const bf16x8*)&Q[base + (size_t)(qrow0 + nq * 16 + l15) * DK + kd * 32 + quad * 8];

    f32x4 oT[5][2] = {};

    ATTN_STAGE(0, Kt0, Vt0)
    for (int kt = 0; kt < SEQ / 64; kt += 2) {
        __syncthreads();
        ATTN_STAGE(kt + 1, Kt1, Vt1)
        ATTN_TILE(Kt0, Vt0)
        __syncthreads();
        if (kt + 2 < SEQ / 64) { ATTN_STAGE(kt + 2, Kt0, Vt0) }
        ATTN_TILE(Kt1, Vt1)
    }

    // epilogue: l = O^T row 64 (quad-0 lanes, reg 0) -> broadcast via shfl
#pragma unroll
    for (int nq = 0; nq < 2; nq++) {
        float lsum = __shfl(oT[4][nq][0], l15);
        float inv = 1.0f / lsum;
        int s = qrow0 + nq * 16 + l15;
#pragma unroll
        for (int mfd = 0; mfd < 4; mfd++) {
            u32x2 u = { pk2(oT[mfd][nq][0] * inv, oT[mfd][nq][1] * inv),
                        pk2(oT[mfd][nq][2] * inv, oT[mfd][nq][3] * inv) };
            *(u32x2*)&O[((size_t)(b * SEQ + s)) * DM + h * 64 + mfd * 16 + quad * 4] = u;
        }
    }
}

// ---------------------------------------------------------------------------
extern "C" void kernel_launch(void* const* d_in, const int* in_sizes, int n_in,
                              void* d_out, int out_size, void* d_ws, size_t ws_size,
                              hipStream_t stream)
{
    const float* q_in = (const float*)d_in[0];
    const float* k_in = (const float*)d_in[1];
    const float* v_in = (const float*)d_in[2];
    const float* Wq = (const float*)d_in[3];
    const float* bq = (const float*)d_in[4];
    const float* Wk = (const float*)d_in[5];
    const float* bk = (const float*)d_in[6];
    const float* Wv = (const float*)d_in[7];
    const float* bv = (const float*)d_in[8];
    const float* Wo = (const float*)d_in[9];
    const float* bo = (const float*)d_in[10];
    float* out = (float*)d_out;

    char* ws = (char*)d_ws;
    const size_t MB = (size_t)1024 * 1024;
    // q,k bf16 parked inside d_out (32 MB fp32), dead before out_proj writes it
    short* qws = (short*)d_out;
    short* kws = (short*)d_out + (size_t)8 * MB;
    const size_t NW = (size_t)DM * DM;

    if (ws_size >= 88 * MB) {
        // fused path: xb0 16 | xb1 16 | xb2 16 | vws 16 | ows 16 | Wb 8
        short* xb0 = (short*)(ws);
        short* xb1 = (short*)(ws + 16 * MB);
        short* xb2 = (short*)(ws + 32 * MB);
        short* vws = (short*)(ws + 48 * MB);
        short* ows = (short*)(ws + 64 * MB);
        short* Wb  = (short*)(ws + 80 * MB);

        cvt_all<<<dim3(14336), 256, 0, stream>>>(q_in, k_in, v_in, Wq, Wk, Wv, Wo, xb0, xb1, xb2, Wb);
        gemm_qkv<<<dim3(8, 64, 3), 256, 0, stream>>>(xb0, xb1, xb2, Wb, bq, bk, bv, qws, kws, vws, 0);
        attn<<<dim3(64, 16), 256, 0, stream>>>(qws, kws, vws, ows);
        out_proj<<<dim3(8, 64), 256, 0, stream>>>(ows, Wb + 3 * NW, bo, out);
    } else {
        // sequential fallback: xb 16 | vws 16 | ows 16 | Wb 8  (56 MB)
        short* xb  = (short*)(ws);
        short* vws = (short*)(ws + 16 * MB);
        short* ows = (short*)(ws + 32 * MB);
        short* Wb  = (short*)(ws + 48 * MB);
        const int xblocks = (4 * SEQ * DM) / 2048;

        cvt_w<<<dim3((int)(NW / 2048), 4), 256, 0, stream>>>(Wq, Wk, Wv, Wo, Wb);
        cvt_x<<<dim3(xblocks), 256, 0, stream>>>(q_in, xb);
        gemm_qkv<<<dim3(8, 64, 1), 256, 0, stream>>>(xb, xb, xb, Wb, bq, bk, bv, qws, kws, vws, 0);
        cvt_x<<<dim3(xblocks), 256, 0, stream>>>(k_in, xb);
        gemm_qkv<<<dim3(8, 64, 1), 256, 0, stream>>>(xb, xb, xb, Wb, bq, bk, bv, qws, kws, vws, 1);
        cvt_x<<<dim3(xblocks), 256, 0, stream>>>(v_in, xb);
        gemm_qkv<<<dim3(8, 64, 1), 256, 0, stream>>>(xb, xb, xb, Wb, bq, bk, bv, qws, kws, vws, 2);
        attn<<<dim3(64, 16), 256, 0, stream>>>(qws, kws, vws, ows);
        out_proj<<<dim3(8, 64), 256, 0, stream>>>(ows, Wb + 3 * NW, bo, out);
    }
}